// Round 2
// baseline (822.269 us; speedup 1.0000x reference)
//
#include <hip/hip_runtime.h>
#include <hip/hip_bf16.h>
#include <math.h>

#define H_ 8
#define DK_ 32
#define B_ 4
#define M_ 64
#define N_ 512
#define D_ 256
#define F_ 1024

static constexpr float SCALE = 0.17677669529663687f; // 1/sqrt(32)
static constexpr float EPS = 1e-5f;

typedef __bf16 bf16x8 __attribute__((ext_vector_type(8)));
typedef float f32x4 __attribute__((ext_vector_type(4)));

// ---------------- dtype detection ----------------
// flags[0] = 1 if float tensors are fp32 (else bf16)
// flags[1] = 1 if mask is uint8 (else int32)
__global__ __launch_bounds__(256) void detect_kernel(const unsigned short* __restrict__ me,
                                                     const unsigned int* __restrict__ mask,
                                                     int* __restrict__ flags) {
    __shared__ int s1[256], s2[256];
    int t = threadIdx.x;
    int cnan = 0;
    for (int i = 0; i < 32; ++i) {
        unsigned short v = me[t * 32 + i];
        if ((v & 0x7F80u) == 0x7F80u) cnan++;
    }
    int cgt = 0;
    for (int i = 0; i < 128; ++i) {
        unsigned int w = mask[t * 128 + i];
        if (w > 1u) cgt++;
    }
    s1[t] = cnan; s2[t] = cgt;
    __syncthreads();
    if (t == 0) {
        int a = 0, b = 0;
        for (int i = 0; i < 256; ++i) { a += s1[i]; b += s2[i]; }
        flags[0] = (a >= 2) ? 1 : 0;
        flags[1] = (b > 0) ? 1 : 0;
    }
}

// ---------------- canonicalize all small float tensors to fp32 ----------------
struct ConvArgs {
    const void* src[26];
    int cum[26];
};

__global__ __launch_bounds__(256) void conv_all_kernel(ConvArgs a, const int* __restrict__ flags,
                                                       float* __restrict__ dst, int total) {
    int i = blockIdx.x * 256 + threadIdx.x;
    if (i >= total) return;
    int t = 0;
    while (i >= a.cum[t]) t++;
    int start = (t == 0) ? 0 : a.cum[t - 1];
    int j = i - start;
    bool f32 = flags[0] != 0;
    float v = f32 ? ((const float*)a.src[t])[j]
                  : __bfloat162float(((const __hip_bfloat16*)a.src[t])[j]);
    dst[i] = v;
}

__global__ __launch_bounds__(256) void conv_mask_kernel(const void* __restrict__ src,
                                                        const int* __restrict__ flags,
                                                        int* __restrict__ dst) {
    int i = blockIdx.x * 256 + threadIdx.x;  // 131072 total
    bool u8 = flags[1] != 0;
    dst[i] = u8 ? (int)((const unsigned char*)src)[i] : ((const int*)src)[i];
}

// ---------------- block reduce helper (256 threads = 4 waves) ----------------
__device__ inline float block_reduce256(float v, bool is_max, float* sbuf) {
#pragma unroll
    for (int off = 32; off > 0; off >>= 1) {
        float o = __shfl_down(v, off, 64);
        v = is_max ? fmaxf(v, o) : (v + o);
    }
    int lane = threadIdx.x & 63, wid = threadIdx.x >> 6;
    if (lane == 0) sbuf[wid] = v;
    __syncthreads();
    float r;
    if (is_max) r = fmaxf(fmaxf(sbuf[0], sbuf[1]), fmaxf(sbuf[2], sbuf[3]));
    else        r = sbuf[0] + sbuf[1] + sbuf[2] + sbuf[3];
    __syncthreads();
    return r;
}

// ---------------- LayerNorm: one block per row of 256 (fp32 in/out) ----------------
__global__ __launch_bounds__(256) void ln_kernel(const float* __restrict__ xin,
                                                 const float* __restrict__ g,
                                                 const float* __restrict__ bta,
                                                 float* __restrict__ out) {
    __shared__ float sbuf[4];
    int row = blockIdx.x, d = threadIdx.x;
    size_t idx = (size_t)row * 256 + d;
    float x = xin[idx];
    float s  = block_reduce256(x, false, sbuf);
    float ss = block_reduce256(x * x, false, sbuf);
    float mu = s * (1.f / 256.f);
    float var = ss * (1.f / 256.f) - mu * mu;
    float y = (x - mu) * rsqrtf(var + EPS) * g[d] + bta[d];
    out[idx] = y;
}

// ---------------- generic projection: Y(rows,N) = X(rows,K) @ W(K,N) + b ----------------
__global__ __launch_bounds__(256) void proj_kernel(const float* __restrict__ X,
                                                   const float* __restrict__ W,
                                                   const float* __restrict__ bias,
                                                   float* __restrict__ Y,
                                                   int K, int Ncols, int relu) {
    int idx = blockIdx.x * 256 + threadIdx.x;
    int row = idx / Ncols;
    int n = idx - row * Ncols;
    const float* xr = X + (size_t)row * K;
    float acc = bias[n];
    for (int k = 0; k < K; ++k)
        acc += xr[k] * W[(size_t)k * Ncols + n];
    if (relu) acc = fmaxf(acc, 0.f);
    Y[idx] = acc;
}

// ---------------- transpose+convert We (256x256 fp32) -> WeT[n][k] bf16 ----------------
__global__ __launch_bounds__(256) void transpose_we(const float* __restrict__ We,
                                                    __hip_bfloat16* __restrict__ WeT) {
    int k = blockIdx.x, n = threadIdx.x;
    WeT[n * 256 + k] = __float2bfloat16(We[k * 256 + n]);
}

// ---------------- big GEMM: eperm(b,h,m,n,dk) = edge(b,n,m,:) @ We + be ----------------
__global__ __launch_bounds__(256) void edge_gemm(const void* __restrict__ A,
                                                 const __hip_bfloat16* __restrict__ WeT,
                                                 const float* __restrict__ be,
                                                 const int* __restrict__ flags,
                                                 __hip_bfloat16* __restrict__ Eperm) {
    __shared__ __align__(16) __bf16 As[64 * 32];
    __shared__ __align__(16) __bf16 Bs[64 * 32];
    const int rowBase = blockIdx.x * 64;
    const int colBase = blockIdx.y * 64;
    const int t = threadIdx.x;
    const int w = t >> 6;
    const int l = t & 63;
    const int lrow = l & 15;
    const int lk8 = (l >> 4) * 8;
    const int ar = t >> 2;
    const int ac = (t & 3) * 8;
    const bool f32 = flags[0] != 0;

    f32x4 acc[4] = {};
    for (int k0 = 0; k0 < 256; k0 += 32) {
        bf16x8 av;
        if (f32) {
            const float* ap = (const float*)A + (size_t)(rowBase + ar) * 256 + k0 + ac;
            float4 x0 = *(const float4*)ap;
            float4 x1 = *(const float4*)(ap + 4);
            av[0] = (__bf16)x0.x; av[1] = (__bf16)x0.y; av[2] = (__bf16)x0.z; av[3] = (__bf16)x0.w;
            av[4] = (__bf16)x1.x; av[5] = (__bf16)x1.y; av[6] = (__bf16)x1.z; av[7] = (__bf16)x1.w;
        } else {
            av = *(const bf16x8*)((const __hip_bfloat16*)A + (size_t)(rowBase + ar) * 256 + k0 + ac);
        }
        bf16x8 bv = *(const bf16x8*)(WeT + (size_t)(colBase + ar) * 256 + k0 + ac);
        __syncthreads();
        *(bf16x8*)(As + ar * 32 + ac) = av;
        *(bf16x8*)(Bs + ar * 32 + ac) = bv;
        __syncthreads();
        bf16x8 afrag = *(const bf16x8*)(As + (w * 16 + lrow) * 32 + lk8);
#pragma unroll
        for (int c = 0; c < 4; ++c) {
            bf16x8 bfrag = *(const bf16x8*)(Bs + (c * 16 + lrow) * 32 + lk8);
            acc[c] = __builtin_amdgcn_mfma_f32_16x16x32_bf16(afrag, bfrag, acc[c], 0, 0, 0);
        }
    }
    int rbase = rowBase + w * 16 + ((l >> 4) * 4);
#pragma unroll
    for (int c = 0; c < 4; ++c) {
        int col = colBase + c * 16 + (l & 15);
        int h = col >> 5, dk = col & 31;
        float bias = be[col];
#pragma unroll
        for (int r = 0; r < 4; ++r) {
            int rg = rbase + r;
            int b = rg >> 15;          // / (N*M)
            int n = (rg >> 6) & 511;
            int m = rg & 63;
            size_t idx = ((((size_t)(b * H_ + h) * M_ + m) * N_ + n) * DK_ + dk);
            Eperm[idx] = __float2bfloat16(acc[c][r] + bias);
        }
    }
}

__device__ inline float bfbits2f(unsigned int b) {
    union { unsigned int i; float f; } c; c.i = b << 16; return c.f;
}

// ---------------- scores: S(b,h,m,n) = sum_d (q+e)(k+e) * SCALE, masked ----------------
__global__ __launch_bounds__(256) void scores_kernel(const float* __restrict__ Q,
                                                     const float* __restrict__ Ko,
                                                     const __hip_bfloat16* __restrict__ Eperm,
                                                     const int* __restrict__ mask,
                                                     float* __restrict__ S) {
    int bhm = blockIdx.x;           // (b*H + h)*M + m
    int m = bhm & 63;
    int h = (bhm >> 6) & 7;
    int b = bhm >> 9;
    __shared__ float sq[32];
    int t = threadIdx.x;
    int w = t >> 6, l = t & 63;
    if (t < 32) sq[t] = Q[(size_t)(b * 64 + m) * 256 + h * 32 + t];
    __syncthreads();
    float qv[32];
#pragma unroll
    for (int i = 0; i < 32; ++i) qv[i] = sq[i];
    const __hip_bfloat16* ebase = Eperm + (size_t)bhm * N_ * DK_;

    for (int it = 0; it < 2; ++it) {
        int n = w * 128 + it * 64 + l;
        const float* kr = Ko + (size_t)(b * 512 + n) * 256 + h * 32;
        float kv[32];
        const float4* kp = (const float4*)kr;
#pragma unroll
        for (int i = 0; i < 8; ++i) {
            float4 v = kp[i];
            kv[4 * i] = v.x; kv[4 * i + 1] = v.y; kv[4 * i + 2] = v.z; kv[4 * i + 3] = v.w;
        }
        float ev[32];
        const uint4* ep = (const uint4*)(ebase + (size_t)n * 32);
#pragma unroll
        for (int i = 0; i < 4; ++i) {
            uint4 u = ep[i];
            ev[8 * i + 0] = bfbits2f(u.x & 0xffffu); ev[8 * i + 1] = bfbits2f(u.x >> 16);
            ev[8 * i + 2] = bfbits2f(u.y & 0xffffu); ev[8 * i + 3] = bfbits2f(u.y >> 16);
            ev[8 * i + 4] = bfbits2f(u.z & 0xffffu); ev[8 * i + 5] = bfbits2f(u.z >> 16);
            ev[8 * i + 6] = bfbits2f(u.w & 0xffffu); ev[8 * i + 7] = bfbits2f(u.w >> 16);
        }
        float s = 0.f;
#pragma unroll
        for (int i = 0; i < 32; ++i) {
            float e = ev[i];
            s += (qv[i] + e) * (kv[i] + e);
        }
        int mk = mask[(size_t)(b * 512 + n) * 64 + m];
        S[(size_t)bhm * 512 + n] = mk ? s * SCALE : -__builtin_inff();
    }
}

// ---------------- softmax over [self, 512 cross] per (b,h,m) ----------------
__global__ __launch_bounds__(256) void softmax_kernel(const float* __restrict__ S,
                                                      const float* __restrict__ Q,
                                                      const float* __restrict__ Ks,
                                                      float* __restrict__ attn,
                                                      float* __restrict__ attn_self) {
    __shared__ float sbuf[4];
    __shared__ float sself;
    int bhm = blockIdx.x;
    int m = bhm & 63;
    int h = (bhm >> 6) & 7;
    int b = bhm >> 9;
    int t = threadIdx.x;
    if (t == 0) {
        const float* q = Q + (size_t)(b * 64 + m) * 256 + h * 32;
        const float* ks = Ks + (size_t)(b * 64 + m) * 256 + h * 32;
        float s = 0.f;
        for (int i = 0; i < 32; ++i) s += q[i] * ks[i];
        sself = s * SCALE;
    }
    __syncthreads();
    float sv = sself;
    float s0 = S[(size_t)bhm * 512 + t];
    float s1 = S[(size_t)bhm * 512 + 256 + t];
    float mx = fmaxf(fmaxf(s0, s1), sv);
    mx = block_reduce256(mx, true, sbuf);
    float e0 = __expf(s0 - mx);
    float e1 = __expf(s1 - mx);
    float eself = __expf(sv - mx);
    float part = e0 + e1 + (t == 0 ? eself : 0.f);
    float sum = block_reduce256(part, false, sbuf);
    float inv = 1.f / sum;
    attn[(size_t)bhm * 512 + t] = e0 * inv;
    attn[(size_t)bhm * 512 + 256 + t] = e1 * inv;
    if (t == 0) attn_self[bhm] = eself * inv;
}

// ---------------- attn output: AO(b,m, h*32+d) ----------------
__global__ __launch_bounds__(256) void attnout_kernel(const float* __restrict__ attn,
                                                      const float* __restrict__ attn_self,
                                                      const float* __restrict__ Vo,
                                                      const float* __restrict__ Vs,
                                                      const __hip_bfloat16* __restrict__ Eperm,
                                                      float* __restrict__ AO) {
    int bhm = blockIdx.x;
    int m = bhm & 63;
    int h = (bhm >> 6) & 7;
    int b = bhm >> 9;
    int t = threadIdx.x;
    int s = t >> 5, d = t & 31;
    const __hip_bfloat16* ebase = Eperm + (size_t)bhm * N_ * DK_;
    float acc = 0.f;
    for (int n = s; n < 512; n += 8) {
        float a = attn[(size_t)bhm * 512 + n];
        float e = __bfloat162float(ebase[(size_t)n * 32 + d]);
        float v = Vo[(size_t)(b * 512 + n) * 256 + h * 32 + d];
        acc += a * (v + e);
    }
    __shared__ float red[256];
    red[t] = acc;
    __syncthreads();
    if (s == 0) {
        float r = red[d] + red[32 + d] + red[64 + d] + red[96 + d]
                + red[128 + d] + red[160 + d] + red[192 + d] + red[224 + d];
        r += attn_self[bhm] * Vs[(size_t)(b * 64 + m) * 256 + h * 32 + d];
        AO[(size_t)(b * 64 + m) * 256 + h * 32 + d] = r;
    }
}

// ---------------- out projection + residual (resid fp32 canonical) ----------------
__global__ __launch_bounds__(256) void oproj_kernel(const float* __restrict__ AO,
                                                    const float* __restrict__ Wo,
                                                    const float* __restrict__ bo,
                                                    const float* __restrict__ resid,
                                                    float* __restrict__ M2) {
    int idx = blockIdx.x * 256 + threadIdx.x;
    int row = idx >> 8, d = idx & 255;
    float acc = bo[d] + resid[idx];
    const float* ar = AO + (size_t)row * 256;
    for (int k = 0; k < 256; ++k)
        acc += ar[k] * Wo[(size_t)k * 256 + d];
    M2[idx] = acc;
}

// ---------------- final: out = M2 + h1 @ Wf2 + bf2 ----------------
__global__ __launch_bounds__(256) void final_kernel(const float* __restrict__ H1,
                                                    const float* __restrict__ Wf2,
                                                    const float* __restrict__ bf2,
                                                    const float* __restrict__ M2,
                                                    const int* __restrict__ flags,
                                                    void* __restrict__ out) {
    int idx = blockIdx.x * 256 + threadIdx.x;
    int row = idx >> 8, d = idx & 255;
    float acc = bf2[d] + M2[idx];
    const float* hr = H1 + (size_t)row * 1024;
    for (int k = 0; k < 1024; ++k)
        acc += hr[k] * Wf2[(size_t)k * 256 + d];
    if (flags[0]) ((float*)out)[idx] = acc;
    else ((__hip_bfloat16*)out)[idx] = __float2bfloat16(acc);
}

extern "C" void kernel_launch(void* const* d_in, const int* in_sizes, int n_in,
                              void* d_out, int out_size, void* d_ws, size_t ws_size,
                              hipStream_t stream) {
    const void* edge_emb = d_in[2];
    const void* o2m_mask = d_in[3];

    // canonical fp32 table: machine, op, Wq,bq, Wk,bk, Wv,bv, Wo,bo, Wks,bks,
    // Wvs,bvs, We,be, g1,bn1, g2,bn2, gop,bnop, Wf1,bf1, Wf2,bf2
    const int srcIdx[26] = {0,1,4,5,6,7,8,9,10,11,12,13,14,15,16,17,18,19,20,21,22,23,24,25,26,27};
    const int sz[26] = {65536,524288, 65536,256, 65536,256, 65536,256, 65536,256,
                        65536,256, 65536,256, 65536,256, 256,256, 256,256, 256,256,
                        262144,1024, 262144,256};
    ConvArgs ca;
    int cum = 0;
    int off[26];
    for (int i = 0; i < 26; ++i) {
        ca.src[i] = d_in[srcIdx[i]];
        off[i] = cum;
        cum += sz[i];
        ca.cum[i] = cum;
    }
    const int TOTAL = cum;   // 1,577,472

    char* p = (char*)d_ws;
    float* canon = (float*)p;                 p += (size_t)TOTAL * 4;
    int* maskI = (int*)p;                     p += 131072 * 4;
    int* flags = (int*)p;                     p += 16;
    float* mnorm = (float*)p;                 p += 65536 * 4;
    float* onorm = (float*)p;                 p += 524288 * 4;
    float* qm    = (float*)p;                 p += 65536 * 4;
    float* kself = (float*)p;                 p += 65536 * 4;
    float* vself = (float*)p;                 p += 65536 * 4;
    float* ko    = (float*)p;                 p += 524288 * 4;
    float* vo    = (float*)p;                 p += 524288 * 4;
    __hip_bfloat16* WeT = (__hip_bfloat16*)p; p += 65536 * 2;
    __hip_bfloat16* eperm = (__hip_bfloat16*)p; p += (size_t)33554432 * 2; // 67 MB
    float* sc    = (float*)p;                 p += (size_t)1048576 * 4;
    float* attn  = (float*)p;                 p += (size_t)1048576 * 4;
    float* attn_self = (float*)p;             p += 2048 * 4;
    float* ao    = (float*)p;                 p += 65536 * 4;
    float* m2    = (float*)p;                 p += 65536 * 4;
    float* hn    = (float*)p;                 p += 65536 * 4;
    float* h1    = (float*)p;                 p += 262144 * 4;

    const float* mF   = canon + off[0];
    const float* oF   = canon + off[1];
    const float* WqF  = canon + off[2],  *bqF  = canon + off[3];
    const float* WkF  = canon + off[4],  *bkF  = canon + off[5];
    const float* WvF  = canon + off[6],  *bvF  = canon + off[7];
    const float* WoF  = canon + off[8],  *boF  = canon + off[9];
    const float* WksF = canon + off[10], *bksF = canon + off[11];
    const float* WvsF = canon + off[12], *bvsF = canon + off[13];
    const float* WeF  = canon + off[14], *beF  = canon + off[15];
    const float* g1F  = canon + off[16], *bn1F = canon + off[17];
    const float* g2F  = canon + off[18], *bn2F = canon + off[19];
    const float* gopF = canon + off[20], *bnopF= canon + off[21];
    const float* Wf1F = canon + off[22], *bf1F = canon + off[23];
    const float* Wf2F = canon + off[24], *bf2F = canon + off[25];

    // 0. dtype detection
    hipLaunchKernelGGL(detect_kernel, dim3(1), dim3(256), 0, stream,
                       (const unsigned short*)d_in[0], (const unsigned int*)o2m_mask, flags);
    // 1. canonicalize
    hipLaunchKernelGGL(conv_all_kernel, dim3((TOTAL + 255) / 256), dim3(256), 0, stream,
                       ca, flags, canon, TOTAL);
    hipLaunchKernelGGL(conv_mask_kernel, dim3(512), dim3(256), 0, stream, o2m_mask, flags, maskI);
    // 2. LayerNorms
    hipLaunchKernelGGL(ln_kernel, dim3(256), dim3(256), 0, stream, mF, g1F, bn1F, mnorm);
    hipLaunchKernelGGL(ln_kernel, dim3(2048), dim3(256), 0, stream, oF, gopF, bnopF, onorm);
    // 3. small projections
    hipLaunchKernelGGL(proj_kernel, dim3(256), dim3(256), 0, stream, mnorm, WqF, bqF, qm, 256, 256, 0);
    hipLaunchKernelGGL(proj_kernel, dim3(256), dim3(256), 0, stream, mnorm, WksF, bksF, kself, 256, 256, 0);
    hipLaunchKernelGGL(proj_kernel, dim3(256), dim3(256), 0, stream, mnorm, WvsF, bvsF, vself, 256, 256, 0);
    hipLaunchKernelGGL(proj_kernel, dim3(2048), dim3(256), 0, stream, onorm, WkF, bkF, ko, 256, 256, 0);
    hipLaunchKernelGGL(proj_kernel, dim3(2048), dim3(256), 0, stream, onorm, WvF, bvF, vo, 256, 256, 0);
    // 4. edge projection (big GEMM) into permuted bf16 layout
    hipLaunchKernelGGL(transpose_we, dim3(256), dim3(256), 0, stream, WeF, WeT);
    hipLaunchKernelGGL(edge_gemm, dim3(2048, 4), dim3(256), 0, stream,
                       edge_emb, WeT, beF, flags, eperm);
    // 5. scores, softmax, attn out
    hipLaunchKernelGGL(scores_kernel, dim3(2048), dim3(256), 0, stream, qm, ko, eperm, maskI, sc);
    hipLaunchKernelGGL(softmax_kernel, dim3(2048), dim3(256), 0, stream, sc, qm, kself, attn, attn_self);
    hipLaunchKernelGGL(attnout_kernel, dim3(2048), dim3(256), 0, stream, attn, attn_self, vo, vself, eperm, ao);
    // 6. out proj + residual, LN2, FFN
    hipLaunchKernelGGL(oproj_kernel, dim3(256), dim3(256), 0, stream, ao, WoF, boF, mF, m2);
    hipLaunchKernelGGL(ln_kernel, dim3(256), dim3(256), 0, stream, m2, g2F, bn2F, hn);
    hipLaunchKernelGGL(proj_kernel, dim3(1024), dim3(256), 0, stream, hn, Wf1F, bf1F, h1, 256, 1024, 1);
    hipLaunchKernelGGL(final_kernel, dim3(256), dim3(256), 0, stream, h1, Wf2F, bf2F, m2, flags, d_out);
}

// Round 4
// 403.836 us; speedup vs baseline: 2.0361x; 2.0361x over previous
//
#include <hip/hip_runtime.h>
#include <hip/hip_bf16.h>
#include <math.h>

#define H_ 8
#define DK_ 32
#define B_ 4
#define M_ 64
#define N_ 512
#define D_ 256
#define F_ 1024

static constexpr float SCALE = 0.17677669529663687f; // 1/sqrt(32)
static constexpr float EPS = 1e-5f;

typedef __bf16 bf16x8 __attribute__((ext_vector_type(8)));
typedef float f32x4 __attribute__((ext_vector_type(4)));

__device__ inline float bfbits2f(unsigned int b) {
    union { unsigned int i; float f; } c; c.i = b << 16; return c.f;
}
__device__ inline void unpack8(uint4 u, float* f) {
    f[0] = bfbits2f(u.x & 0xffffu); f[1] = bfbits2f(u.x >> 16);
    f[2] = bfbits2f(u.y & 0xffffu); f[3] = bfbits2f(u.y >> 16);
    f[4] = bfbits2f(u.z & 0xffffu); f[5] = bfbits2f(u.z >> 16);
    f[6] = bfbits2f(u.w & 0xffffu); f[7] = bfbits2f(u.w >> 16);
}

// ---------------- mask dtype detection (uint8 vs int32 bools) ----------------
__global__ __launch_bounds__(256) void detect_kernel(const unsigned int* __restrict__ mask,
                                                     int* __restrict__ flags) {
    __shared__ int s2[256];
    int t = threadIdx.x;
    int cgt = 0;
    for (int i = 0; i < 128; ++i) {
        unsigned int w = mask[t * 128 + i];
        if (w > 1u) cgt++;
    }
    s2[t] = cgt;
    __syncthreads();
    if (t == 0) {
        int b = 0;
        for (int i = 0; i < 256; ++i) b += s2[i];
        flags[1] = (b > 0) ? 1 : 0;
    }
}

// maskT[(b*64+m)*512+n] = mask[(b*512+n)*64+m]
__global__ __launch_bounds__(256) void conv_maskT_kernel(const void* __restrict__ src,
                                                         const int* __restrict__ flags,
                                                         int* __restrict__ dst) {
    int i = blockIdx.x * 256 + threadIdx.x;  // 131072
    int b = i >> 15, m = (i >> 9) & 63, n = i & 511;
    int si = (b * 512 + n) * 64 + m;
    bool u8 = flags[1] != 0;
    dst[i] = u8 ? (int)((const unsigned char*)src)[si] : ((const int*)src)[si];
}

// ---------------- weight transpose+convert: dst[n*K+k] = bf16(src[k*N+n]) ----------------
struct TransArgs {
    const void* src[9];
    void* dst[9];
    int cum[9];
    int kl[9];   // log2 K
    int nl[9];   // log2 N
};

__global__ __launch_bounds__(256) void prep_transpose(TransArgs a, int total) {
    int i = blockIdx.x * 256 + threadIdx.x;
    if (i >= total) return;
    int t = 0;
    while (i >= a.cum[t]) t++;
    int j = i - (t == 0 ? 0 : a.cum[t - 1]);
    int K = 1 << a.kl[t];
    int n = j >> a.kl[t];
    int k = j & (K - 1);
    float v = ((const float*)a.src[t])[((size_t)k << a.nl[t]) + n];
    ((__hip_bfloat16*)a.dst[t])[j] = __float2bfloat16(v);
}

__global__ __launch_bounds__(256) void prep_bias(const float* bq, const float* bks,
                                                 const float* bvs, const float* bk,
                                                 const float* bv,
                                                 float* bqksvs, float* bkv) {
    int t = threadIdx.x;
    bqksvs[t] = bq[t];
    bqksvs[256 + t] = bks[t];
    bqksvs[512 + t] = bvs[t];
    bkv[t] = bk[t];
    bkv[256 + t] = bv[t];
}

// ---------------- block reduce (256 threads = 4 waves) ----------------
__device__ inline float block_reduce256(float v, bool is_max, float* sbuf) {
#pragma unroll
    for (int off = 32; off > 0; off >>= 1) {
        float o = __shfl_down(v, off, 64);
        v = is_max ? fmaxf(v, o) : (v + o);
    }
    int lane = threadIdx.x & 63, wid = threadIdx.x >> 6;
    if (lane == 0) sbuf[wid] = v;
    __syncthreads();
    float r;
    if (is_max) r = fmaxf(fmaxf(sbuf[0], sbuf[1]), fmaxf(sbuf[2], sbuf[3]));
    else        r = sbuf[0] + sbuf[1] + sbuf[2] + sbuf[3];
    __syncthreads();
    return r;
}

// ---------------- LayerNorm: fp32 in -> bf16 out ----------------
__global__ __launch_bounds__(256) void ln_kernel(const float* __restrict__ xin,
                                                 const float* __restrict__ g,
                                                 const float* __restrict__ bta,
                                                 __hip_bfloat16* __restrict__ out) {
    __shared__ float sbuf[4];
    int row = blockIdx.x, d = threadIdx.x;
    size_t idx = (size_t)row * 256 + d;
    float x = xin[idx];
    float s  = block_reduce256(x, false, sbuf);
    float ss = block_reduce256(x * x, false, sbuf);
    float mu = s * (1.f / 256.f);
    float var = ss * (1.f / 256.f) - mu * mu;
    float y = (x - mu) * rsqrtf(var + EPS) * g[d] + bta[d];
    out[idx] = __float2bfloat16(y);
}

// ---------------- generic MFMA GEMM: out(M,ldc) = A(M,K) @ BT(N,K)^T + bias ----------------
// flags: 1=relu, 4=resid f32, 8=out f32 (else bf16)
__global__ __launch_bounds__(256) void gemm64(const __hip_bfloat16* __restrict__ A,
                                              const __hip_bfloat16* __restrict__ BT,
                                              const float* __restrict__ bias,
                                              const float* __restrict__ resid,
                                              void* __restrict__ out,
                                              int K, int ldc, int flags) {
    __shared__ __align__(16) __bf16 As[64 * 32];
    __shared__ __align__(16) __bf16 Bs[64 * 32];
    const int rowBase = blockIdx.x * 64;
    const int colBase = blockIdx.y * 64;
    const int t = threadIdx.x;
    const int w = t >> 6;
    const int l = t & 63;
    const int lrow = l & 15;
    const int lk8 = (l >> 4) * 8;
    const int ar = t >> 2;
    const int ac = (t & 3) * 8;

    f32x4 acc[4] = {};
    for (int k0 = 0; k0 < K; k0 += 32) {
        bf16x8 av = *(const bf16x8*)(A + (size_t)(rowBase + ar) * K + k0 + ac);
        bf16x8 bv = *(const bf16x8*)(BT + (size_t)(colBase + ar) * K + k0 + ac);
        __syncthreads();
        *(bf16x8*)(As + ar * 32 + ac) = av;
        *(bf16x8*)(Bs + ar * 32 + ac) = bv;
        __syncthreads();
        bf16x8 af = *(const bf16x8*)(As + (w * 16 + lrow) * 32 + lk8);
#pragma unroll
        for (int c = 0; c < 4; ++c) {
            bf16x8 bf = *(const bf16x8*)(Bs + (c * 16 + lrow) * 32 + lk8);
            acc[c] = __builtin_amdgcn_mfma_f32_16x16x32_bf16(af, bf, acc[c], 0, 0, 0);
        }
    }
    int rbase = rowBase + w * 16 + ((l >> 4) * 4);
#pragma unroll
    for (int c = 0; c < 4; ++c) {
        int col = colBase + c * 16 + (l & 15);
        float bb = bias[col];
#pragma unroll
        for (int r = 0; r < 4; ++r) {
            int row = rbase + r;
            size_t oi = (size_t)row * ldc + col;
            float v = acc[c][r] + bb;
            if (flags & 1) v = fmaxf(v, 0.f);
            if (flags & 4) v += resid[oi];
            if (flags & 8) ((float*)out)[oi] = v;
            else ((__hip_bfloat16*)out)[oi] = __float2bfloat16(v);
        }
    }
}

// ---------------- edge GEMM: one block per (b,n); out eperm(b,h,m,n,dk) bf16 ----------------
__global__ __launch_bounds__(256) void edge_gemm2(const float* __restrict__ E,
                                                  const __hip_bfloat16* __restrict__ WeT,
                                                  const float* __restrict__ be,
                                                  __hip_bfloat16* __restrict__ eperm) {
    __shared__ __align__(16) char smem[64 * 272 * 2];   // 34816 B
    __bf16* As = (__bf16*)smem;              // 64 x 32
    __bf16* Bs = (__bf16*)(smem + 4096);     // 256 x 32
    __bf16* Cs = (__bf16*)smem;              // 64 x 272 (reuses As/Bs after K-loop)
    const int bn = blockIdx.x;               // b*512 + n
    const int t = threadIdx.x;
    const int w = t >> 6;
    const int l = t & 63;
    const int lrow = l & 15;
    const int lk8 = (l >> 4) * 8;
    const int ar = t >> 2;
    const int ac = (t & 3) * 8;
    const float* Ab = E + (size_t)bn * 64 * 256;

    f32x4 acc[4][4] = {};
    for (int k0 = 0; k0 < 256; k0 += 32) {
        const float* ap = Ab + (size_t)ar * 256 + k0 + ac;
        float4 x0 = *(const float4*)ap;
        float4 x1 = *(const float4*)(ap + 4);
        bf16x8 av;
        av[0] = (__bf16)x0.x; av[1] = (__bf16)x0.y; av[2] = (__bf16)x0.z; av[3] = (__bf16)x0.w;
        av[4] = (__bf16)x1.x; av[5] = (__bf16)x1.y; av[6] = (__bf16)x1.z; av[7] = (__bf16)x1.w;
        bf16x8 bv[4];
#pragma unroll
        for (int j = 0; j < 4; ++j)
            bv[j] = *(const bf16x8*)(WeT + (size_t)t * 256 + k0 + j * 8);
        __syncthreads();
        *(bf16x8*)(As + ar * 32 + ac) = av;
#pragma unroll
        for (int j = 0; j < 4; ++j)
            *(bf16x8*)(Bs + t * 32 + j * 8) = bv[j];
        __syncthreads();
        bf16x8 af[4];
#pragma unroll
        for (int rr = 0; rr < 4; ++rr)
            af[rr] = *(const bf16x8*)(As + (rr * 16 + lrow) * 32 + lk8);
#pragma unroll
        for (int c = 0; c < 4; ++c) {
            bf16x8 bf = *(const bf16x8*)(Bs + (w * 64 + c * 16 + lrow) * 32 + lk8);
#pragma unroll
            for (int rr = 0; rr < 4; ++rr)
                acc[rr][c] = __builtin_amdgcn_mfma_f32_16x16x32_bf16(af[rr], bf, acc[rr][c], 0, 0, 0);
        }
    }
    __syncthreads();
    // stage C (64 m x 256 d) in LDS, padded stride 272
#pragma unroll
    for (int c = 0; c < 4; ++c) {
        int col = w * 64 + c * 16 + (l & 15);
        float bb = be[col];
#pragma unroll
        for (int rr = 0; rr < 4; ++rr) {
#pragma unroll
            for (int r = 0; r < 4; ++r) {
                int m = rr * 16 + (l >> 4) * 4 + r;
                Cs[m * 272 + col] = (__bf16)(acc[rr][c][r] + bb);
            }
        }
    }
    __syncthreads();
    int b = bn >> 9, n = bn & 511;
#pragma unroll
    for (int j = 0; j < 8; ++j) {
        int flat = j * 256 + t;          // (m, d8) pair
        int m = flat >> 5, seg = flat & 31;
        int h = seg >> 2, dk8 = (seg & 3) * 8;
        size_t oi = (((size_t)((b * 8 + h) * 64 + m) * 512) + n) * 32 + dk8;
        *(uint4*)(eperm + oi) = *(const uint4*)(Cs + m * 272 + seg * 8);
    }
}

// ---------------- scores: eperm(b,h,m,n,dk) ----------------
__global__ __launch_bounds__(256) void scores_kernel(const __hip_bfloat16* __restrict__ qkvs,
                                                     const __hip_bfloat16* __restrict__ kov,
                                                     const __hip_bfloat16* __restrict__ eperm,
                                                     const int* __restrict__ maskT,
                                                     float* __restrict__ S) {
    int bhm = blockIdx.x;           // (b*H + h)*M + m
    int m = bhm & 63;
    int h = (bhm >> 6) & 7;
    int b = bhm >> 9;
    __shared__ float sq[32];
    int t = threadIdx.x;
    int w = t >> 6, l = t & 63;
    if (t < 32) sq[t] = __bfloat162float(qkvs[(size_t)(b * 64 + m) * 768 + h * 32 + t]);
    __syncthreads();
    float qv[32];
#pragma unroll
    for (int i = 0; i < 32; ++i) qv[i] = sq[i];
    const __hip_bfloat16* ebase = eperm + (size_t)bhm * 512 * 32;

    for (int it = 0; it < 2; ++it) {
        int n = w * 128 + it * 64 + l;
        float kv[32], ev[32];
        const uint4* kp = (const uint4*)(kov + (size_t)(b * 512 + n) * 512 + h * 32);
        const uint4* ep = (const uint4*)(ebase + (size_t)n * 32);
#pragma unroll
        for (int i = 0; i < 4; ++i) unpack8(kp[i], kv + 8 * i);
#pragma unroll
        for (int i = 0; i < 4; ++i) unpack8(ep[i], ev + 8 * i);
        float s = 0.f;
#pragma unroll
        for (int i = 0; i < 32; ++i) {
            float e = ev[i];
            s += (qv[i] + e) * (kv[i] + e);
        }
        int mk = maskT[(size_t)(b * 64 + m) * 512 + n];
        S[(size_t)bhm * 512 + n] = mk ? s * SCALE : -__builtin_inff();
    }
}

// ---------------- softmax over [self, 512] ----------------
__global__ __launch_bounds__(256) void softmax_kernel(const float* __restrict__ S,
                                                      const __hip_bfloat16* __restrict__ qkvs,
                                                      float* __restrict__ attn,
                                                      float* __restrict__ attn_self) {
    __shared__ float sbuf[4];
    __shared__ float sself;
    int bhm = blockIdx.x;
    int m = bhm & 63;
    int h = (bhm >> 6) & 7;
    int b = bhm >> 9;
    int t = threadIdx.x;
    if (t == 0) {
        const __hip_bfloat16* q  = qkvs + (size_t)(b * 64 + m) * 768 + h * 32;
        const __hip_bfloat16* ks = qkvs + (size_t)(b * 64 + m) * 768 + 256 + h * 32;
        float s = 0.f;
        for (int i = 0; i < 32; ++i) s += __bfloat162float(q[i]) * __bfloat162float(ks[i]);
        sself = s * SCALE;
    }
    __syncthreads();
    float sv = sself;
    float s0 = S[(size_t)bhm * 512 + t];
    float s1 = S[(size_t)bhm * 512 + 256 + t];
    float mx = fmaxf(fmaxf(s0, s1), sv);
    mx = block_reduce256(mx, true, sbuf);
    float e0 = __expf(s0 - mx);
    float e1 = __expf(s1 - mx);
    float eself = __expf(sv - mx);
    float part = e0 + e1 + (t == 0 ? eself : 0.f);
    float sum = block_reduce256(part, false, sbuf);
    float inv = 1.f / sum;
    attn[(size_t)bhm * 512 + t] = e0 * inv;
    attn[(size_t)bhm * 512 + 256 + t] = e1 * inv;
    if (t == 0) attn_self[bhm] = eself * inv;
}

// ---------------- attn output -> AO bf16 (b*64+m, 256) ----------------
__global__ __launch_bounds__(256) void attnout_kernel(const float* __restrict__ attn,
                                                      const float* __restrict__ attn_self,
                                                      const __hip_bfloat16* __restrict__ kov,
                                                      const __hip_bfloat16* __restrict__ qkvs,
                                                      const __hip_bfloat16* __restrict__ eperm,
                                                      __hip_bfloat16* __restrict__ AO) {
    int bhm = blockIdx.x;
    int m = bhm & 63;
    int h = (bhm >> 6) & 7;
    int b = bhm >> 9;
    int t = threadIdx.x;
    int s = t >> 5, d = t & 31;
    const __hip_bfloat16* ebase = eperm + (size_t)bhm * 512 * 32;
    float acc = 0.f;
    for (int n = s; n < 512; n += 8) {
        float a = attn[(size_t)bhm * 512 + n];
        float e = __bfloat162float(ebase[(size_t)n * 32 + d]);
        float v = __bfloat162float(kov[(size_t)(b * 512 + n) * 512 + 256 + h * 32 + d]);
        acc += a * (v + e);
    }
    __shared__ float red[256];
    red[t] = acc;
    __syncthreads();
    if (s == 0) {
        float r = red[d] + red[32 + d] + red[64 + d] + red[96 + d]
                + red[128 + d] + red[160 + d] + red[192 + d] + red[224 + d];
        float vs = __bfloat162float(qkvs[(size_t)(b * 64 + m) * 768 + 512 + h * 32 + d]);
        r += attn_self[bhm] * vs;
        AO[(size_t)(b * 64 + m) * 256 + h * 32 + d] = __float2bfloat16(r);
    }
}

extern "C" void kernel_launch(void* const* d_in, const int* in_sizes, int n_in,
                              void* d_out, int out_size, void* d_ws, size_t ws_size,
                              hipStream_t stream) {
    const float* machine_emb = (const float*)d_in[0];
    const float* op_emb      = (const float*)d_in[1];
    const float* edge_emb    = (const float*)d_in[2];
    const void*  o2m_mask    = d_in[3];

    char* p = (char*)d_ws;
    int* flags = (int*)p;                        p += 256;
    int* maskT = (int*)p;                        p += 131072 * 4;
    __hip_bfloat16* WqksvsT = (__hip_bfloat16*)p; p += 196608 * 2;
    __hip_bfloat16* WkvT    = (__hip_bfloat16*)p; p += 131072 * 2;
    __hip_bfloat16* WoT     = (__hip_bfloat16*)p; p += 65536 * 2;
    __hip_bfloat16* WeT     = (__hip_bfloat16*)p; p += 65536 * 2;
    __hip_bfloat16* Wf1T    = (__hip_bfloat16*)p; p += 262144 * 2;
    __hip_bfloat16* Wf2T    = (__hip_bfloat16*)p; p += 262144 * 2;
    float* bqksvs           = (float*)p;          p += 768 * 4;
    float* bkv              = (float*)p;          p += 512 * 4;
    __hip_bfloat16* mnorm   = (__hip_bfloat16*)p; p += 65536 * 2;
    __hip_bfloat16* onorm   = (__hip_bfloat16*)p; p += 524288 * 2;
    __hip_bfloat16* qkvs    = (__hip_bfloat16*)p; p += 196608 * 2;
    __hip_bfloat16* kov     = (__hip_bfloat16*)p; p += 1048576 * 2;
    __hip_bfloat16* eperm   = (__hip_bfloat16*)p; p += (size_t)33554432 * 2;
    float* sc        = (float*)p;                p += (size_t)1048576 * 4;
    float* attn      = (float*)p;                p += (size_t)1048576 * 4;
    float* attn_self = (float*)p;                p += 2048 * 4;
    __hip_bfloat16* AO = (__hip_bfloat16*)p;     p += 65536 * 2;
    float* m2        = (float*)p;                p += 65536 * 4;
    __hip_bfloat16* hn = (__hip_bfloat16*)p;     p += 65536 * 2;
    __hip_bfloat16* h1 = (__hip_bfloat16*)p;     p += 262144 * 2;

    // prep: transpose+convert all weights to (N,K) bf16
    TransArgs ta;
    const int srcIdx[9] = {4, 12, 14, 6, 8, 10, 16, 24, 26};
    void* dsts[9] = {WqksvsT, WqksvsT + 65536, WqksvsT + 131072,
                     WkvT, WkvT + 65536, WoT, WeT, Wf1T, Wf2T};
    const int sizes9[9] = {65536, 65536, 65536, 65536, 65536, 65536, 65536, 262144, 262144};
    const int kl9[9] = {8, 8, 8, 8, 8, 8, 8, 8, 10};
    const int nl9[9] = {8, 8, 8, 8, 8, 8, 8, 10, 8};
    int cum = 0;
    for (int i = 0; i < 9; ++i) {
        ta.src[i] = d_in[srcIdx[i]];
        ta.dst[i] = dsts[i];
        cum += sizes9[i];
        ta.cum[i] = cum;
        ta.kl[i] = kl9[i];
        ta.nl[i] = nl9[i];
    }

    hipLaunchKernelGGL(detect_kernel, dim3(1), dim3(256), 0, stream,
                       (const unsigned int*)o2m_mask, flags);
    hipLaunchKernelGGL(prep_transpose, dim3((cum + 255) / 256), dim3(256), 0, stream, ta, cum);
    hipLaunchKernelGGL(prep_bias, dim3(1), dim3(256), 0, stream,
                       (const float*)d_in[5], (const float*)d_in[13],
                       (const float*)d_in[15], (const float*)d_in[7],
                       (const float*)d_in[9], bqksvs, bkv);
    hipLaunchKernelGGL(conv_maskT_kernel, dim3(512), dim3(256), 0, stream, o2m_mask, flags, maskT);

    // LayerNorms (fp32 in -> bf16 out)
    hipLaunchKernelGGL(ln_kernel, dim3(256), dim3(256), 0, stream,
                       machine_emb, (const float*)d_in[18], (const float*)d_in[19], mnorm);
    hipLaunchKernelGGL(ln_kernel, dim3(2048), dim3(256), 0, stream,
                       op_emb, (const float*)d_in[22], (const float*)d_in[23], onorm);

    // projections (MFMA)
    hipLaunchKernelGGL(gemm64, dim3(4, 12), dim3(256), 0, stream,
                       mnorm, WqksvsT, bqksvs, nullptr, qkvs, 256, 768, 0);
    hipLaunchKernelGGL(gemm64, dim3(32, 8), dim3(256), 0, stream,
                       onorm, WkvT, bkv, nullptr, kov, 256, 512, 0);

    // edge GEMM -> eperm(b,h,m,n,dk)
    hipLaunchKernelGGL(edge_gemm2, dim3(2048), dim3(256), 0, stream,
                       edge_emb, WeT, (const float*)d_in[17], eperm);

    // attention
    hipLaunchKernelGGL(scores_kernel, dim3(2048), dim3(256), 0, stream, qkvs, kov, eperm, maskT, sc);
    hipLaunchKernelGGL(softmax_kernel, dim3(2048), dim3(256), 0, stream, sc, qkvs, attn, attn_self);
    hipLaunchKernelGGL(attnout_kernel, dim3(2048), dim3(256), 0, stream,
                       attn, attn_self, kov, qkvs, eperm, AO);

    // out proj + residual -> m2 (f32), LN2, FFN
    hipLaunchKernelGGL(gemm64, dim3(4, 4), dim3(256), 0, stream,
                       AO, WoT, (const float*)d_in[11], machine_emb, m2, 256, 256, 4 | 8);
    hipLaunchKernelGGL(ln_kernel, dim3(256), dim3(256), 0, stream,
                       m2, (const float*)d_in[20], (const float*)d_in[21], hn);
    hipLaunchKernelGGL(gemm64, dim3(4, 16), dim3(256), 0, stream,
                       hn, Wf1T, (const float*)d_in[25], nullptr, h1, 256, 1024, 1);
    hipLaunchKernelGGL(gemm64, dim3(4, 4), dim3(256), 0, stream,
                       h1, Wf2T, (const float*)d_in[27], m2, (float*)d_out, 1024, 256, 4 | 8);
}